// Round 4
// baseline (208.174 us; speedup 1.0000x reference)
//
#include <hip/hip_runtime.h>
#include <stdint.h>

// EdgeAwareMultiHeadAttention on MI355X (gfx950) — round 4
// Changes vs round 3:
//  * flash: BARRIER-FREE main loop. K/V read directly from global in
//    fragment-major (pre-swizzled) layout -> no K/V LDS staging, no
//    __syncthreads in the j-loop. LDS only for the P roundtrip.
//  * flash: S^T formulation (MFMA(kf,qf)) -> lanes hold consecutive j:
//    adjacency as float4 loads (4 instr, was 16), P written as ds_write_b64
//    (4 instr, was 16 b16), O^T=MFMA(vf,pf). lsum is a single register.
//  * gemm_qkv epilogue writes K->ksw and V->vsw in fragment-major layout
//    (index permutation on the existing scalar stores). vtrans DELETED.
//  * gemm_out retiled to 64x64 (512 blocks, 2/CU).

#define SEQ 2048
#define EMB 512
#define NH  8
#define HD  64
#define NB  2
#define L2E 1.4426950408889634f

typedef unsigned int   u32;
typedef unsigned short u16;
typedef u32   u32x4  __attribute__((ext_vector_type(4)));
typedef float f32x4  __attribute__((ext_vector_type(4)));
typedef __bf16 bf16x8 __attribute__((ext_vector_type(8)));

#define MFMA16(a, b, c) __builtin_amdgcn_mfma_f32_16x16x32_bf16((a), (b), (c), 0, 0, 0)

static __device__ __forceinline__ u16 f2bf(float f) {
  return __builtin_bit_cast(u16, (__bf16)f);
}
static __device__ __forceinline__ u32 pack2(float a, float b) {
  return (u32)f2bf(a) | ((u32)f2bf(b) << 16);
}
static __device__ __forceinline__ bf16x8 ldfrag(const u16* p) {
  return __builtin_bit_cast(bf16x8, *(const u32x4*)p);
}

// Fragment-major layouts, per (b,h) plane of 131072 u16 (2048x64):
//  ksw: element (n,d) at (n>>4)*1024 + (d>>5)*512 + (((d>>3)&3)*16 + (n&15))*8 + (d&7)
//       -> flash reads kf = base + jtile*1024 + kc*512 + lane*8  (coalesced 16B/lane)
//  vsw: element (n,d) at (n>>6)*4096 + (d>>4)*1024 + ((n>>5)&1)*512
//                      + (((n>>3)&3)*16 + (d&15))*8 + (n&7)
//       -> flash reads vf = base + jchunk*4096 + dt*1024 + kc*512 + lane*8

// ---------------------------------------------------------------- prep
__global__ void prep_kernel(const float* __restrict__ x,
                            const float* __restrict__ Wq, const float* __restrict__ Wk,
                            const float* __restrict__ Wv, const float* __restrict__ Wo,
                            const float* __restrict__ We1, const float* __restrict__ be1,
                            const float* __restrict__ We2, const float* __restrict__ be2,
                            const float* __restrict__ ebias,
                            u16* __restrict__ xb, u16* __restrict__ wqkv,
                            u16* __restrict__ wob, float* __restrict__ co) {
  const int blk = blockIdx.x, tid = threadIdx.x;
  if (blk < 2048) {
    int i = (blk * 256 + tid) * 4;
    float4 v = *(const float4*)(x + i);
    *(uint2*)(xb + i) = make_uint2(pack2(v.x, v.y), pack2(v.z, v.w));
  } else if (blk < 3072) {
    int i = ((blk - 2048) * 256 + tid) * 4;
    int m = i >> 18;
    int off = i & 262143;
    const float* src = (m == 0) ? Wq : ((m == 1) ? Wk : ((m == 2) ? Wv : Wo));
    u16* dst = (m < 3) ? (wqkv + (size_t)m * 262144) : wob;
    float4 v = *(const float4*)(src + off);
    *(uint2*)(dst + off) = make_uint2(pack2(v.x, v.y), pack2(v.z, v.w));
  } else {
    const int e = tid & 15, h = tid >> 4;
    if (tid < 128) {
      co[49 + e * 8 + h] = 0.0f;
      if (h == 0) { co[17 + e] = 0.0f; co[33 + e] = 0.0f; }
    }
    __syncthreads();
    if (tid < 128) {
      float w1 = We1[e], b1 = be1[e], w2 = We2[h * 16 + e];
      float u0 = b1, u1 = w1 + b1;
      bool on  = (u0 >= 0.0f) && (u1 >= 0.0f);
      bool off = (u0 <= 0.0f) && (u1 <= 0.0f);
      bool crossing = (!on) && (!off);
      float ca = on ? (w2 * b1) : (crossing ? 0.5f * w2 * b1 : 0.0f);
      float cb = on ? (w2 * w1) : (crossing ? 0.5f * w2 * w1 : 0.0f);
      #pragma unroll
      for (int d = 1; d < 16; d <<= 1) { ca += __shfl_xor(ca, d); cb += __shfl_xor(cb, d); }
      if (e == 0) { co[h] = (be2[h] + ca) * L2E; co[8 + h] = (ebias[h] + cb) * L2E; }
      unsigned long long msk = __ballot(crossing);
      int midx = __popcll(msk & 0xFFFFull & ((1ull << e) - 1ull));
      int mcnt = __popcll(msk & 0xFFFFull);
      if (crossing) {
        co[49 + midx * 8 + h] = 0.5f * w2 * L2E;
        if (h == 0) { co[17 + midx] = w1; co[33 + midx] = b1; }
      }
      if (tid == 0) ((int*)co)[16] = mcnt;
    }
  }
}

// ---------------------------------------------------------------- k1: QKV GEMM 64x128
#define LDA 40
__global__ __launch_bounds__(256) void gemm_qkv_kernel(
    const u16* __restrict__ A, const u16* __restrict__ Bm,
    const float* __restrict__ bq, const float* __restrict__ bk, const float* __restrict__ bv,
    u16* __restrict__ qh, u16* __restrict__ ksw, u16* __restrict__ vsw)
{
  __shared__ u16 As[64 * LDA];
  __shared__ u16 Bs[128 * LDA];
  const int tid = threadIdx.x;
  const int lane = tid & 63, w = tid >> 6;
  const int q = lane >> 4, l15 = lane & 15;
  const int m0 = blockIdx.y * 64;
  const int n0 = blockIdx.x * 128;

  f32x4 acc[4][2];
  f32x4 zero = {0.f, 0.f, 0.f, 0.f};
  #pragma unroll
  for (int i = 0; i < 4; i++) { acc[i][0] = zero; acc[i][1] = zero; }

  const bool isA = tid < 128;
  const int arow = tid >> 1, ahalf = tid & 1;
  const int brow = tid - 128;
  const u16* ga = A  + (size_t)(m0 + arow) * EMB + ahalf * 16;
  const u16* gb = Bm + (size_t)(n0 + brow) * EMB;
  u16* la = &As[arow * LDA + ahalf * 16];
  u16* lb = &Bs[brow * LDA];

  u32x4 p0, p1, p2, p3;
  if (isA) {
    p0 = *(const u32x4*)(ga); p1 = *(const u32x4*)(ga + 8); ga += 32;
  } else {
    p0 = *(const u32x4*)(gb);      p1 = *(const u32x4*)(gb + 8);
    p2 = *(const u32x4*)(gb + 16); p3 = *(const u32x4*)(gb + 24); gb += 32;
  }

  for (int k0 = 0; k0 < EMB; k0 += 32) {
    __syncthreads();
    if (isA) { *(u32x4*)(la) = p0; *(u32x4*)(la + 8) = p1; }
    else {
      *(u32x4*)(lb)      = p0; *(u32x4*)(lb + 8)  = p1;
      *(u32x4*)(lb + 16) = p2; *(u32x4*)(lb + 24) = p3;
    }
    __syncthreads();
    if (k0 + 32 < EMB) {
      if (isA) { p0 = *(const u32x4*)(ga); p1 = *(const u32x4*)(ga + 8); ga += 32; }
      else {
        p0 = *(const u32x4*)(gb);      p1 = *(const u32x4*)(gb + 8);
        p2 = *(const u32x4*)(gb + 16); p3 = *(const u32x4*)(gb + 24); gb += 32;
      }
    }
    bf16x8 af[4], bfr[2];
    #pragma unroll
    for (int mi = 0; mi < 4; mi++)
      af[mi] = ldfrag(&As[(mi*16 + l15) * LDA + q*8]);
    #pragma unroll
    for (int ni = 0; ni < 2; ni++)
      bfr[ni] = ldfrag(&Bs[(w*32 + ni*16 + l15) * LDA + q*8]);
    #pragma unroll
    for (int mi = 0; mi < 4; mi++)
      #pragma unroll
      for (int ni = 0; ni < 2; ni++)
        acc[mi][ni] = MFMA16(af[mi], bfr[ni], acc[mi][ni]);
  }

  const int mat = n0 >> 9;                // 0:Q 1:K 2:V

  #pragma unroll
  for (int mi = 0; mi < 4; mi++) {
    int rowb = m0 + mi*16 + q*4;
    #pragma unroll
    for (int ni = 0; ni < 2; ni++) {
      int col = n0 + w*32 + ni*16 + l15;
      int oo = col & 511;
      int hh = oo >> 6, dd = oo & 63;
      if (mat == 0) {
        float bsv = bq[oo];
        #pragma unroll
        for (int r = 0; r < 4; r++) {
          int grow = rowb + r;
          int b_ = grow >> 11, n_ = grow & 2047;
          float val = (acc[mi][ni][r] + bsv) * (0.125f * L2E);  // scale*log2e folded
          qh[((size_t)(b_ * NH + hh) * SEQ + n_) * HD + dd] = f2bf(val);
        }
      } else if (mat == 1) {
        float bsv = bk[oo];
        #pragma unroll
        for (int r = 0; r < 4; r++) {
          int grow = rowb + r;
          int b_ = grow >> 11, n_ = grow & 2047;
          float val = acc[mi][ni][r] + bsv;
          size_t addr = (size_t)(b_ * NH + hh) * 131072
                      + (n_ >> 4) * 1024 + ((dd >> 5) << 9)
                      + ((((dd >> 3) & 3) * 16 + (n_ & 15)) << 3) + (dd & 7);
          ksw[addr] = f2bf(val);
        }
      } else {
        float bsv = bv[oo];
        #pragma unroll
        for (int r = 0; r < 4; r++) {
          int grow = rowb + r;
          int b_ = grow >> 11, n_ = grow & 2047;
          float val = acc[mi][ni][r] + bsv;
          size_t addr = (size_t)(b_ * NH + hh) * 131072
                      + (n_ >> 6) * 4096 + ((dd >> 4) << 10) + (((n_ >> 5) & 1) << 9)
                      + ((((n_ >> 3) & 3) * 16 + (dd & 15)) << 3) + (n_ & 7);
          vsw[addr] = f2bf(val);
        }
      }
    }
  }
}

// ---------------------------------------------------------------- k3: out GEMM 64x64
__global__ __launch_bounds__(256) void gemm_out_kernel(
    const u16* __restrict__ A, const u16* __restrict__ Bm,
    const float* __restrict__ bo, float* __restrict__ out)
{
  __shared__ u16 As[64 * LDA];
  __shared__ u16 Bs[64 * LDA];
  const int tid = threadIdx.x;
  const int lane = tid & 63, w = tid >> 6;
  const int q = lane >> 4, l15 = lane & 15;
  const int m0 = blockIdx.y * 64;
  const int n0 = blockIdx.x * 64;

  f32x4 acc[4];
  f32x4 zero = {0.f, 0.f, 0.f, 0.f};
  #pragma unroll
  for (int i = 0; i < 4; i++) acc[i] = zero;

  const bool isA = tid < 128;
  const int row = isA ? (tid >> 1) : ((tid - 128) >> 1);
  const int half = tid & 1;
  const u16* g = (isA ? A + (size_t)(m0 + row) * EMB : Bm + (size_t)(n0 + row) * EMB)
               + half * 16;
  u16* l = (isA ? &As[row * LDA] : &Bs[row * LDA]) + half * 16;

  u32x4 p0 = *(const u32x4*)(g);
  u32x4 p1 = *(const u32x4*)(g + 8);
  g += 32;

  for (int k0 = 0; k0 < EMB; k0 += 32) {
    __syncthreads();
    *(u32x4*)(l) = p0; *(u32x4*)(l + 8) = p1;
    __syncthreads();
    if (k0 + 32 < EMB) {
      p0 = *(const u32x4*)(g); p1 = *(const u32x4*)(g + 8); g += 32;
    }
    bf16x8 af[4], bfr;
    #pragma unroll
    for (int mi = 0; mi < 4; mi++)
      af[mi] = ldfrag(&As[(mi*16 + l15) * LDA + q*8]);
    bfr = ldfrag(&Bs[(w*16 + l15) * LDA + q*8]);
    #pragma unroll
    for (int mi = 0; mi < 4; mi++)
      acc[mi] = MFMA16(af[mi], bfr, acc[mi]);
  }

  int col = n0 + w*16 + l15;
  float bsv = bo[col];
  #pragma unroll
  for (int mi = 0; mi < 4; mi++) {
    int rowb = m0 + mi*16 + q*4;
    #pragma unroll
    for (int r = 0; r < 4; r++)
      out[(size_t)(rowb + r) * EMB + col] = acc[mi][r] + bsv;
  }
}

// ---------------------------------------------------------------- k2: flash (barrier-free)
// 512 thr = 8 waves. Wave w: i-rows i0+(w&3)*16, j-half (w>>2)*1024, 16 iters of 64 j.
// S^T = MFMA(kf, qf): lane(q,l15) holds (j = jt*16+q*4+r, i = l15).
// O^T = MFMA(vf, pf): lane(q,l15) holds (d = dt*16+q*4+r, i = l15).
template<int MT>
__device__ __forceinline__ void flash_body(
    u16* __restrict__ smem,
    const u16* __restrict__ qh, const u16* __restrict__ ksw, const u16* __restrict__ vsw,
    const float* __restrict__ adj, const float* __restrict__ coeff, u16* __restrict__ om)
{
  const int tid = threadIdx.x, lane = tid & 63, w = tid >> 6;
  const int q = lane >> 4, l15 = lane & 15;
  const int i0 = blockIdx.x * 64;
  const int h = blockIdx.y, b = blockIdx.z;
  const int bh = b * NH + h;
  const int iw = i0 + (w & 3) * 16;
  const int jbase = (w >> 2) * 1024;

  const float Ah = coeff[h], Bh = coeff[8 + h];
  float ctr[MT], dtr[MT], wtr[MT];
  #pragma unroll
  for (int t = 0; t < MT; t++) {
    ctr[t] = coeff[17 + t];
    dtr[t] = coeff[33 + t];
    wtr[t] = coeff[49 + t * 8 + h];
  }

  const u16* qrow = qh + ((size_t)bh * SEQ + iw + l15) * HD;
  bf16x8 qf0 = ldfrag(qrow + q * 8);          // d 0..31  (B-operand)
  bf16x8 qf1 = ldfrag(qrow + 32 + q * 8);     // d 32..63

  const u16* kbase = ksw + (size_t)bh * 131072 + jbase * 64 + lane * 8;
  const u16* vbase = vsw + (size_t)bh * 131072 + jbase * 64 + lane * 8;
  const float* arow = adj + ((size_t)b * SEQ + iw + l15) * SEQ + jbase + q * 4;

  f32x4 O[4];
  f32x4 zero = {0.f, 0.f, 0.f, 0.f};
  #pragma unroll
  for (int dt = 0; dt < 4; dt++) O[dt] = zero;
  float lsum = 0.0f;

  u16* psw = smem + w * 16 * 72;    // per-wave P tile [i=l15][j], stride 72 u16

  for (int it = 0; it < 16; it++) {
    const int off = it * 4096;      // u16 offset per 64-j step in frag-major layout

    // K fragments + adjacency (all coalesced / float4)
    bf16x8 kf[8];
    #pragma unroll
    for (int jt = 0; jt < 4; jt++) {
      kf[jt*2]   = ldfrag(kbase + off + jt * 1024);
      kf[jt*2+1] = ldfrag(kbase + off + jt * 1024 + 512);
    }
    float4 av[4];
    #pragma unroll
    for (int jt = 0; jt < 4; jt++)
      av[jt] = *(const float4*)(arow + it * 64 + jt * 16);

    // S^T
    f32x4 S[4];
    #pragma unroll
    for (int jt = 0; jt < 4; jt++) {
      f32x4 s = MFMA16(kf[jt*2], qf0, zero);
      S[jt] = MFMA16(kf[jt*2+1], qf1, s);
    }

    // V fragments (issued early; consumed after the VALU block below)
    bf16x8 vf[8];
    #pragma unroll
    for (int dt = 0; dt < 4; dt++) {
      vf[dt*2]   = ldfrag(vbase + off + dt * 1024);
      vf[dt*2+1] = ldfrag(vbase + off + dt * 1024 + 512);
    }

    // edge bias + exp2 + P pack/write (4 x ds_write_b64)
    #pragma unroll
    for (int jt = 0; jt < 4; jt++) {
      float p[4];
      #pragma unroll
      for (int r = 0; r < 4; r++) {
        float a = ((const float*)&av[jt])[r];
        float e = fmaf(a, Bh, Ah);
        #pragma unroll
        for (int t = 0; t < MT; t++)
          e = fmaf(fabsf(fmaf(a, ctr[t], dtr[t])), wtr[t], e);
        p[r] = __builtin_amdgcn_exp2f(S[jt][r] + e);
        lsum += p[r];
      }
      *(uint2*)(psw + l15 * 72 + jt * 16 + q * 4) =
          make_uint2(pack2(p[0], p[1]), pack2(p[2], p[3]));
    }

    // O^T += V^T P^T (same-wave LDS write->read, in-order)
    bf16x8 pf0 = ldfrag(psw + l15 * 72 + q * 8);        // j 0..31
    bf16x8 pf1 = ldfrag(psw + l15 * 72 + 32 + q * 8);   // j 32..63
    #pragma unroll
    for (int dt = 0; dt < 4; dt++) {
      O[dt] = MFMA16(vf[dt*2],   pf0, O[dt]);
      O[dt] = MFMA16(vf[dt*2+1], pf1, O[dt]);
    }
  }

  // full row-sum for i=l15 over this j-half: reduce across the 4 quads
  lsum += __shfl_xor(lsum, 16);
  lsum += __shfl_xor(lsum, 32);

  // combine j-halves through LDS (reuse smem), then store O[i][d]
  __syncthreads();
  float* fbuf = (float*)smem;                  // [(w&3)*64+lane]*17 floats
  if (w >= 4) {
    int bi = ((w & 3) * 64 + lane) * 17;
    #pragma unroll
    for (int dt = 0; dt < 4; dt++)
      #pragma unroll
      for (int r = 0; r < 4; r++) fbuf[bi + dt * 4 + r] = O[dt][r];
    fbuf[bi + 16] = lsum;
  }
  __syncthreads();
  if (w < 4) {
    int bi = (w * 64 + lane) * 17;
    float rl = 1.0f / (lsum + fbuf[bi + 16]);
    u16* orow = om + ((size_t)b * SEQ + iw + l15) * EMB + h * HD + q * 4;
    #pragma unroll
    for (int dt = 0; dt < 4; dt++) {
      float v0 = (O[dt][0] + fbuf[bi + dt * 4 + 0]) * rl;
      float v1 = (O[dt][1] + fbuf[bi + dt * 4 + 1]) * rl;
      float v2 = (O[dt][2] + fbuf[bi + dt * 4 + 2]) * rl;
      float v3 = (O[dt][3] + fbuf[bi + dt * 4 + 3]) * rl;
      *(uint2*)(orow + dt * 16) = make_uint2(pack2(v0, v1), pack2(v2, v3));
    }
  }
}

__global__ __launch_bounds__(512, 4) void flash_kernel(
    const u16* __restrict__ qh, const u16* __restrict__ ksw, const u16* __restrict__ vsw,
    const float* __restrict__ adj, const float* __restrict__ coeff, u16* __restrict__ om)
{
  __shared__ __align__(16) u16 smem[8 * 16 * 72];   // 18432 B
  const int mt = ((const int*)coeff)[16];
  if (mt <= 4)      flash_body<4>(smem, qh, ksw, vsw, adj, coeff, om);
  else if (mt <= 8) flash_body<8>(smem, qh, ksw, vsw, adj, coeff, om);
  else              flash_body<16>(smem, qh, ksw, vsw, adj, coeff, om);
}

// ---------------------------------------------------------------- launch
extern "C" void kernel_launch(void* const* d_in, const int* in_sizes, int n_in,
                              void* d_out, int out_size, void* d_ws, size_t ws_size,
                              hipStream_t stream) {
  const float* x     = (const float*)d_in[0];
  const float* adj   = (const float*)d_in[1];
  const float* Wq    = (const float*)d_in[2];
  const float* bq    = (const float*)d_in[3];
  const float* Wk    = (const float*)d_in[4];
  const float* bk    = (const float*)d_in[5];
  const float* Wv    = (const float*)d_in[6];
  const float* bv    = (const float*)d_in[7];
  const float* Wo    = (const float*)d_in[8];
  const float* bo    = (const float*)d_in[9];
  const float* We1   = (const float*)d_in[10];
  const float* be1   = (const float*)d_in[11];
  const float* We2   = (const float*)d_in[12];
  const float* be2   = (const float*)d_in[13];
  const float* ebias = (const float*)d_in[14];
  float* out = (float*)d_out;

  char* ws = (char*)d_ws;
  u16*   xb   = (u16*)(ws + 0);          //  4 MB  x bf16
  u16*   wqkv = (u16*)(ws + 4194304);    //  1.5MB Wq|Wk|Wv bf16
  u16*   wob  = (u16*)(ws + 5767168);    //  0.5MB Wo bf16
  u16*   qh   = (u16*)(ws + 6291456);    //  4 MB  (B,H,N,64) row-major
  u16*   ksw  = (u16*)(ws + 10485760);   //  4 MB  fragment-major K
  u16*   vsw  = (u16*)(ws + 14680064);   //  4 MB  fragment-major V
  u16*   om   = (u16*)(ws + 18874368);   //  4 MB  (B,N,512) bf16
  float* co   = (float*)(ws + 23068672); //  1 KB  edge coefficients
  if (ws_size < 23069696) return;

  prep_kernel<<<3073, 256, 0, stream>>>(x, Wq, Wk, Wv, Wo, We1, be1, We2, be2, ebias,
                                        xb, wqkv, wob, co);
  gemm_qkv_kernel<<<dim3(12, 64), 256, 0, stream>>>(xb, wqkv, bq, bk, bv, qh, ksw, vsw);
  flash_kernel<<<dim3(32, NH, NB), 512, 0, stream>>>(qh, ksw, vsw, adj, co, om);
  gemm_out_kernel<<<dim3(8, 64), 256, 0, stream>>>(om, wob, bo, out);
}

// Round 5
// 201.027 us; speedup vs baseline: 1.0356x; 1.0356x over previous
//
#include <hip/hip_runtime.h>
#include <stdint.h>

// EdgeAwareMultiHeadAttention on MI355X (gfx950) — round 5
// Changes vs round 4:
//  * flash: explicit software pipeline — kf reloaded for t+1 right after its
//    S-MFMAs (WAR rotation, no double buffer), av[jt] reloaded right after its
//    edge-math, vf split around the kf reload. Loads now in flight across
//    ~500+ cyc of compute instead of exposed at iteration top (VGPR=64 r4
//    showed compiler was issuing them just-in-time).
//  * flash: 256-thread blocks, full j-range per block (32 iters) -> no j-half
//    combine epilogue; __launch_bounds__(256,3) gives allocator ~168 VGPRs.
//  * gemm_qkv: epilogue stages Q/K/V output tiles through LDS (swizzled
//    scalar writes) then stores 8KB CONTIGUOUS per head — the r4 frag-major
//    scatter was 2-byte stores across 4-8 lines/wave-instr (L2 RMW).

#define SEQ 2048
#define EMB 512
#define NH  8
#define HD  64
#define NB  2
#define L2E 1.4426950408889634f

typedef unsigned int   u32;
typedef unsigned short u16;
typedef u32   u32x4  __attribute__((ext_vector_type(4)));
typedef float f32x4  __attribute__((ext_vector_type(4)));
typedef __bf16 bf16x8 __attribute__((ext_vector_type(8)));

#define MFMA16(a, b, c) __builtin_amdgcn_mfma_f32_16x16x32_bf16((a), (b), (c), 0, 0, 0)

static __device__ __forceinline__ u16 f2bf(float f) {
  return __builtin_bit_cast(u16, (__bf16)f);
}
static __device__ __forceinline__ u32 pack2(float a, float b) {
  return (u32)f2bf(a) | ((u32)f2bf(b) << 16);
}
static __device__ __forceinline__ bf16x8 ldfrag(const u16* p) {
  return __builtin_bit_cast(bf16x8, *(const u32x4*)p);
}

// Fragment-major layouts, per (b,h) plane of 131072 u16 (2048x64):
//  ksw: (n,d) -> (n>>4)*1024 + (d>>5)*512 + (((d>>3)&3)*16 + (n&15))*8 + (d&7)
//  vsw: (n,d) -> (n>>6)*4096 + (d>>4)*1024 + ((n>>5)&1)*512
//               + (((n>>3)&3)*16 + (d&15))*8 + (n&7)

// ---------------------------------------------------------------- prep
__global__ void prep_kernel(const float* __restrict__ x,
                            const float* __restrict__ Wq, const float* __restrict__ Wk,
                            const float* __restrict__ Wv, const float* __restrict__ Wo,
                            const float* __restrict__ We1, const float* __restrict__ be1,
                            const float* __restrict__ We2, const float* __restrict__ be2,
                            const float* __restrict__ ebias,
                            u16* __restrict__ xb, u16* __restrict__ wqkv,
                            u16* __restrict__ wob, float* __restrict__ co) {
  const int blk = blockIdx.x, tid = threadIdx.x;
  if (blk < 2048) {
    int i = (blk * 256 + tid) * 4;
    float4 v = *(const float4*)(x + i);
    *(uint2*)(xb + i) = make_uint2(pack2(v.x, v.y), pack2(v.z, v.w));
  } else if (blk < 3072) {
    int i = ((blk - 2048) * 256 + tid) * 4;
    int m = i >> 18;
    int off = i & 262143;
    const float* src = (m == 0) ? Wq : ((m == 1) ? Wk : ((m == 2) ? Wv : Wo));
    u16* dst = (m < 3) ? (wqkv + (size_t)m * 262144) : wob;
    float4 v = *(const float4*)(src + off);
    *(uint2*)(dst + off) = make_uint2(pack2(v.x, v.y), pack2(v.z, v.w));
  } else {
    const int e = tid & 15, h = tid >> 4;
    if (tid < 128) {
      co[49 + e * 8 + h] = 0.0f;
      if (h == 0) { co[17 + e] = 0.0f; co[33 + e] = 0.0f; }
    }
    __syncthreads();
    if (tid < 128) {
      float w1 = We1[e], b1 = be1[e], w2 = We2[h * 16 + e];
      float u0 = b1, u1 = w1 + b1;
      bool on  = (u0 >= 0.0f) && (u1 >= 0.0f);
      bool off = (u0 <= 0.0f) && (u1 <= 0.0f);
      bool crossing = (!on) && (!off);
      float ca = on ? (w2 * b1) : (crossing ? 0.5f * w2 * b1 : 0.0f);
      float cb = on ? (w2 * w1) : (crossing ? 0.5f * w2 * w1 : 0.0f);
      #pragma unroll
      for (int d = 1; d < 16; d <<= 1) { ca += __shfl_xor(ca, d); cb += __shfl_xor(cb, d); }
      if (e == 0) { co[h] = (be2[h] + ca) * L2E; co[8 + h] = (ebias[h] + cb) * L2E; }
      unsigned long long msk = __ballot(crossing);
      int midx = __popcll(msk & 0xFFFFull & ((1ull << e) - 1ull));
      int mcnt = __popcll(msk & 0xFFFFull);
      if (crossing) {
        co[49 + midx * 8 + h] = 0.5f * w2 * L2E;
        if (h == 0) { co[17 + midx] = w1; co[33 + midx] = b1; }
      }
      if (tid == 0) ((int*)co)[16] = mcnt;
    }
  }
}

// ---------------------------------------------------------------- k1: QKV GEMM 64x128
#define LDA 40
__global__ __launch_bounds__(256) void gemm_qkv_kernel(
    const u16* __restrict__ A, const u16* __restrict__ Bm,
    const float* __restrict__ bq, const float* __restrict__ bk, const float* __restrict__ bv,
    u16* __restrict__ qh, u16* __restrict__ ksw, u16* __restrict__ vsw)
{
  __shared__ u16 sm[64 * LDA + 128 * LDA];   // As | Bs, reused by epilogue
  u16* As = sm;
  u16* Bs = sm + 64 * LDA;
  const int tid = threadIdx.x;
  const int lane = tid & 63, w = tid >> 6;
  const int q = lane >> 4, l15 = lane & 15;
  const int m0 = blockIdx.y * 64;
  const int n0 = blockIdx.x * 128;

  f32x4 acc[4][2];
  f32x4 zero = {0.f, 0.f, 0.f, 0.f};
  #pragma unroll
  for (int i = 0; i < 4; i++) { acc[i][0] = zero; acc[i][1] = zero; }

  const bool isA = tid < 128;
  const int arow_ = tid >> 1, ahalf = tid & 1;
  const int brow = tid - 128;
  const u16* ga = A  + (size_t)(m0 + arow_) * EMB + ahalf * 16;
  const u16* gb = Bm + (size_t)(n0 + brow) * EMB;
  u16* la = &As[arow_ * LDA + ahalf * 16];
  u16* lb = &Bs[brow * LDA];

  u32x4 p0, p1, p2, p3;
  if (isA) {
    p0 = *(const u32x4*)(ga); p1 = *(const u32x4*)(ga + 8); ga += 32;
  } else {
    p0 = *(const u32x4*)(gb);      p1 = *(const u32x4*)(gb + 8);
    p2 = *(const u32x4*)(gb + 16); p3 = *(const u32x4*)(gb + 24); gb += 32;
  }

  for (int k0 = 0; k0 < EMB; k0 += 32) {
    __syncthreads();
    if (isA) { *(u32x4*)(la) = p0; *(u32x4*)(la + 8) = p1; }
    else {
      *(u32x4*)(lb)      = p0; *(u32x4*)(lb + 8)  = p1;
      *(u32x4*)(lb + 16) = p2; *(u32x4*)(lb + 24) = p3;
    }
    __syncthreads();
    if (k0 + 32 < EMB) {
      if (isA) { p0 = *(const u32x4*)(ga); p1 = *(const u32x4*)(ga + 8); ga += 32; }
      else {
        p0 = *(const u32x4*)(gb);      p1 = *(const u32x4*)(gb + 8);
        p2 = *(const u32x4*)(gb + 16); p3 = *(const u32x4*)(gb + 24); gb += 32;
      }
    }
    bf16x8 af[4], bfr[2];
    #pragma unroll
    for (int mi = 0; mi < 4; mi++)
      af[mi] = ldfrag(&As[(mi*16 + l15) * LDA + q*8]);
    #pragma unroll
    for (int ni = 0; ni < 2; ni++)
      bfr[ni] = ldfrag(&Bs[(w*32 + ni*16 + l15) * LDA + q*8]);
    #pragma unroll
    for (int mi = 0; mi < 4; mi++)
      #pragma unroll
      for (int ni = 0; ni < 2; ni++)
        acc[mi][ni] = MFMA16(af[mi], bfr[ni], acc[mi][ni]);
  }

  // -------- epilogue: LDS-staged, per-head coalesced stores --------
  const int mat = n0 >> 9;                // 0:Q 1:K 2:V
  const float* bias = (mat == 0) ? bq : ((mat == 1) ? bk : bv);
  const float mul = (mat == 0) ? 0.125f * L2E : 1.0f;
  const int b_ = m0 >> 11;
  const int nbase = m0 & 2047;

  #pragma unroll
  for (int p = 0; p < 2; p++) {           // one head per pass
    __syncthreads();
    if ((w >> 1) == p) {
      #pragma unroll
      for (int ni = 0; ni < 2; ni++) {
        const int dd = (w & 1) * 32 + ni * 16 + l15;
        const float bsv = bias[(n0 & 511) + (w * 32 + ni * 16 + l15)];
        #pragma unroll
        for (int mi = 0; mi < 4; mi++) {
          #pragma unroll
          for (int r = 0; r < 4; r++) {
            const int nr = mi * 16 + q * 4 + r;        // n rel. to nbase
            const float val = (acc[mi][ni][r] + bsv) * mul;
            int idx;
            if (mat == 0)      idx = nr * 64 + dd;
            else if (mat == 1) idx = (nr >> 4) * 1024 + ((dd >> 5) << 9)
                                   + ((((dd >> 3) & 3) * 16 + (nr & 15)) << 3) + (dd & 7);
            else               idx = ((dd >> 4) << 10) + (((nr >> 5) & 1) << 9)
                                   + ((((nr >> 3) & 3) * 16 + (dd & 15)) << 3) + (nr & 7);
            sm[idx] = f2bf(val);
          }
        }
      }
    }
    __syncthreads();
    const int hh = ((n0 & 511) >> 6) + p;
    u16* gdst;
    if (mat == 0)      gdst = qh  + ((size_t)(b_ * NH + hh) * SEQ + nbase) * HD;
    else if (mat == 1) gdst = ksw + (size_t)(b_ * NH + hh) * 131072 + (nbase >> 4) * 1024;
    else               gdst = vsw + (size_t)(b_ * NH + hh) * 131072 + (nbase >> 6) * 4096;
    *(u32x4*)(gdst + tid * 16)     = *(const u32x4*)(sm + tid * 16);
    *(u32x4*)(gdst + tid * 16 + 8) = *(const u32x4*)(sm + tid * 16 + 8);
  }
}

// ---------------------------------------------------------------- k3: out GEMM 64x64
__global__ __launch_bounds__(256) void gemm_out_kernel(
    const u16* __restrict__ A, const u16* __restrict__ Bm,
    const float* __restrict__ bo, float* __restrict__ out)
{
  __shared__ u16 As[64 * LDA];
  __shared__ u16 Bs[64 * LDA];
  const int tid = threadIdx.x;
  const int lane = tid & 63, w = tid >> 6;
  const int q = lane >> 4, l15 = lane & 15;
  const int m0 = blockIdx.y * 64;
  const int n0 = blockIdx.x * 64;

  f32x4 acc[4];
  f32x4 zero = {0.f, 0.f, 0.f, 0.f};
  #pragma unroll
  for (int i = 0; i < 4; i++) acc[i] = zero;

  const bool isA = tid < 128;
  const int row = isA ? (tid >> 1) : ((tid - 128) >> 1);
  const int half = tid & 1;
  const u16* g = (isA ? A + (size_t)(m0 + row) * EMB : Bm + (size_t)(n0 + row) * EMB)
               + half * 16;
  u16* l = (isA ? &As[row * LDA] : &Bs[row * LDA]) + half * 16;

  u32x4 p0 = *(const u32x4*)(g);
  u32x4 p1 = *(const u32x4*)(g + 8);
  g += 32;

  for (int k0 = 0; k0 < EMB; k0 += 32) {
    __syncthreads();
    *(u32x4*)(l) = p0; *(u32x4*)(l + 8) = p1;
    __syncthreads();
    if (k0 + 32 < EMB) {
      p0 = *(const u32x4*)(g); p1 = *(const u32x4*)(g + 8); g += 32;
    }
    bf16x8 af[4], bfr;
    #pragma unroll
    for (int mi = 0; mi < 4; mi++)
      af[mi] = ldfrag(&As[(mi*16 + l15) * LDA + q*8]);
    bfr = ldfrag(&Bs[(w*16 + l15) * LDA + q*8]);
    #pragma unroll
    for (int mi = 0; mi < 4; mi++)
      acc[mi] = MFMA16(af[mi], bfr, acc[mi]);
  }

  int col = n0 + w*16 + l15;
  float bsv = bo[col];
  #pragma unroll
  for (int mi = 0; mi < 4; mi++) {
    int rowb = m0 + mi*16 + q*4;
    #pragma unroll
    for (int r = 0; r < 4; r++)
      out[(size_t)(rowb + r) * EMB + col] = acc[mi][r] + bsv;
  }
}

// ---------------------------------------------------------------- k2: flash (pipelined)
// 256 thr = 4 waves. Wave w: i-rows i0+w*16, FULL j range (32 iters of 64 j).
// S^T = MFMA(kf,qf): lane(q,l15) = (j=jt*16+q*4+r, i=l15).
// O^T = MFMA(vf,pf): lane(q,l15) = (d=dt*16+q*4+r, i=l15).
template<int MT>
__device__ __forceinline__ void flash_body(
    u16* __restrict__ smem,
    const u16* __restrict__ qh, const u16* __restrict__ ksw, const u16* __restrict__ vsw,
    const float* __restrict__ adj, const float* __restrict__ coeff, u16* __restrict__ om)
{
  const int tid = threadIdx.x, lane = tid & 63, w = tid >> 6;
  const int q = lane >> 4, l15 = lane & 15;
  const int i0 = blockIdx.x * 64;
  const int h = blockIdx.y, b = blockIdx.z;
  const int bh = b * NH + h;
  const int iw = i0 + w * 16;

  const float Ah = coeff[h], Bh = coeff[8 + h];
  float ctr[MT], dtr[MT], wtr[MT];
  #pragma unroll
  for (int t = 0; t < MT; t++) {
    ctr[t] = coeff[17 + t];
    dtr[t] = coeff[33 + t];
    wtr[t] = coeff[49 + t * 8 + h];
  }

  const u16* qrow = qh + ((size_t)bh * SEQ + iw + l15) * HD;
  bf16x8 qf0 = ldfrag(qrow + q * 8);
  bf16x8 qf1 = ldfrag(qrow + 32 + q * 8);

  const u16* kbase = ksw + (size_t)bh * 131072 + lane * 8;
  const u16* vbase = vsw + (size_t)bh * 131072 + lane * 8;
  const float* arow = adj + ((size_t)b * SEQ + iw + l15) * SEQ + q * 4;

  f32x4 O[4];
  f32x4 zero = {0.f, 0.f, 0.f, 0.f};
  #pragma unroll
  for (int dt = 0; dt < 4; dt++) O[dt] = zero;
  float lsum = 0.0f;

  u16* psw = smem + w * 16 * 72;

  // prologue: K fragments + adjacency for iter 0
  bf16x8 kf[8];
  float4 av[4];
  #pragma unroll
  for (int jt = 0; jt < 4; jt++) {
    kf[jt*2]   = ldfrag(kbase + jt * 1024);
    kf[jt*2+1] = ldfrag(kbase + jt * 1024 + 512);
    av[jt] = *(const float4*)(arow + jt * 16);
  }

  #pragma unroll 1
  for (int it = 0; it < 32; it++) {
    const int off = it * 4096;
    const int nx = (it + 1 < 32) ? it + 1 : 31;
    const int noff = nx * 4096;

    // first half of V loads (in flight across S + edge)
    bf16x8 vf[8];
    #pragma unroll
    for (int dt = 0; dt < 2; dt++) {
      vf[dt*2]   = ldfrag(vbase + off + dt * 1024);
      vf[dt*2+1] = ldfrag(vbase + off + dt * 1024 + 512);
    }

    // S^T from current kf
    f32x4 S[4];
    #pragma unroll
    for (int jt = 0; jt < 4; jt++) {
      f32x4 s = MFMA16(kf[jt*2], qf0, zero);
      S[jt] = MFMA16(kf[jt*2+1], qf1, s);
    }

    // rotate: issue next-iter K loads now (WAR on kf; in flight across edge+PV)
    #pragma unroll
    for (int jt = 0; jt < 4; jt++) {
      kf[jt*2]   = ldfrag(kbase + noff + jt * 1024);
      kf[jt*2+1] = ldfrag(kbase + noff + jt * 1024 + 512);
    }
    // second half of V loads
    #pragma unroll
    for (int dt = 2; dt < 4; dt++) {
      vf[dt*2]   = ldfrag(vbase + off + dt * 1024);
      vf[dt*2+1] = ldfrag(vbase + off + dt * 1024 + 512);
    }

    // edge bias + exp2 + P pack/write; av[jt] reloaded right after consumption
    #pragma unroll
    for (int jt = 0; jt < 4; jt++) {
      float p[4];
      #pragma unroll
      for (int r = 0; r < 4; r++) {
        float a = ((const float*)&av[jt])[r];
        float e = fmaf(a, Bh, Ah);
        #pragma unroll
        for (int t = 0; t < MT; t++)
          e = fmaf(fabsf(fmaf(a, ctr[t], dtr[t])), wtr[t], e);
        p[r] = __builtin_amdgcn_exp2f(S[jt][r] + e);
        lsum += p[r];
      }
      av[jt] = *(const float4*)(arow + nx * 64 + jt * 16);
      *(uint2*)(psw + l15 * 72 + jt * 16 + q * 4) =
          make_uint2(pack2(p[0], p[1]), pack2(p[2], p[3]));
    }

    // O^T += V^T P^T
    bf16x8 pf0 = ldfrag(psw + l15 * 72 + q * 8);
    bf16x8 pf1 = ldfrag(psw + l15 * 72 + 32 + q * 8);
    #pragma unroll
    for (int dt = 0; dt < 4; dt++) {
      O[dt] = MFMA16(vf[dt*2],   pf0, O[dt]);
      O[dt] = MFMA16(vf[dt*2+1], pf1, O[dt]);
    }
  }

  // full row-sum for i=l15 (reduce across the 4 quads)
  lsum += __shfl_xor(lsum, 16);
  lsum += __shfl_xor(lsum, 32);
  float rl = 1.0f / lsum;

  u16* orow = om + ((size_t)b * SEQ + iw + l15) * EMB + h * HD + q * 4;
  #pragma unroll
  for (int dt = 0; dt < 4; dt++) {
    float v0 = O[dt][0] * rl, v1 = O[dt][1] * rl;
    float v2 = O[dt][2] * rl, v3 = O[dt][3] * rl;
    *(uint2*)(orow + dt * 16) = make_uint2(pack2(v0, v1), pack2(v2, v3));
  }
}

__global__ __launch_bounds__(256, 3) void flash_kernel(
    const u16* __restrict__ qh, const u16* __restrict__ ksw, const u16* __restrict__ vsw,
    const float* __restrict__ adj, const float* __restrict__ coeff, u16* __restrict__ om)
{
  __shared__ __align__(16) u16 smem[4 * 16 * 72];   // 9216 B
  const int mt = ((const int*)coeff)[16];
  if (mt <= 4)      flash_body<4>(smem, qh, ksw, vsw, adj, coeff, om);
  else if (mt <= 8) flash_body<8>(smem, qh, ksw, vsw, adj, coeff, om);
  else              flash_body<16>(smem, qh, ksw, vsw, adj, coeff, om);
}

// ---------------------------------------------------------------- launch
extern "C" void kernel_launch(void* const* d_in, const int* in_sizes, int n_in,
                              void* d_out, int out_size, void* d_ws, size_t ws_size,
                              hipStream_t stream) {
  const float* x     = (const float*)d_in[0];
  const float* adj   = (const float*)d_in[1];
  const float* Wq    = (const float*)d_in[2];
  const float* bq    = (const float*)d_in[3];
  const float* Wk    = (const float*)d_in[4];
  const float* bk    = (const float*)d_in[5];
  const float* Wv    = (const float*)d_in[6];
  const float* bv    = (const float*)d_in[7];
  const float* Wo    = (const float*)d_in[8];
  const float* bo    = (const float*)d_in[9];
  const float* We1   = (const float*)d_in[10];
  const float* be1   = (const float*)d_in[11];
  const float* We2   = (const float*)d_in[12];
  const float* be2   = (const float*)d_in[13];
  const float* ebias = (const float*)d_in[14];
  float* out = (float*)d_out;

  char* ws = (char*)d_ws;
  u16*   xb   = (u16*)(ws + 0);          //  4 MB  x bf16
  u16*   wqkv = (u16*)(ws + 4194304);    //  1.5MB Wq|Wk|Wv bf16
  u16*   wob  = (u16*)(ws + 5767168);    //  0.5MB Wo bf16
  u16*   qh   = (u16*)(ws + 6291456);    //  4 MB  (B,H,N,64) row-major
  u16*   ksw  = (u16*)(ws + 10485760);   //  4 MB  fragment-major K
  u16*   vsw  = (u16*)(ws + 14680064);   //  4 MB  fragment-major V
  u16*   om   = (u16*)(ws + 18874368);   //  4 MB  (B,N,512) bf16
  float* co   = (float*)(ws + 23068672); //  1 KB  edge coefficients
  if (ws_size < 23069696) return;

  prep_kernel<<<3073, 256, 0, stream>>>(x, Wq, Wk, Wv, Wo, We1, be1, We2, be2, ebias,
                                        xb, wqkv, wob, co);
  gemm_qkv_kernel<<<dim3(12, 64), 256, 0, stream>>>(xb, wqkv, bq, bk, bv, qh, ksw, vsw);
  flash_kernel<<<dim3(32, NH, NB), 256, 0, stream>>>(qh, ksw, vsw, adj, co, om);
  gemm_out_kernel<<<dim3(8, 64), 256, 0, stream>>>(om, wob, bo, out);
}

// Round 6
// 193.267 us; speedup vs baseline: 1.0771x; 1.0402x over previous
//
#include <hip/hip_runtime.h>
#include <stdint.h>

// EdgeAwareMultiHeadAttention on MI355X (gfx950) — round 6
// Changes vs round 5 (flash only; other kernels byte-identical to r5):
//  * flash: K/V staged ONCE PER BLOCK via global_load_lds width=16 into a
//    double-buffered LDS image of the fragment-major layout (r4/r5 had all
//    4 waves issuing identical K/V loads -> 4x redundant VMEM).
//  * prefetch for tile t+1 issued AFTER the barrier gating tile t, so the
//    barrier's vmcnt(0) drain only waits loads issued a full iteration
//    earlier -> drain-free double buffering (unlike m97's 20% stall).
//  * adjacency register-double-buffered with role swap via 2x unroll
//    (no WAR serialization); sched_barrier(0) pins prefetch above compute.
//  * fragments re-read per wave via conflict-free ds_read_b128.

#define SEQ 2048
#define EMB 512
#define NH  8
#define HD  64
#define NB  2
#define L2E 1.4426950408889634f

typedef unsigned int   u32;
typedef unsigned short u16;
typedef u32   u32x4  __attribute__((ext_vector_type(4)));
typedef float f32x4  __attribute__((ext_vector_type(4)));
typedef __bf16 bf16x8 __attribute__((ext_vector_type(8)));

#define MFMA16(a, b, c) __builtin_amdgcn_mfma_f32_16x16x32_bf16((a), (b), (c), 0, 0, 0)

static __device__ __forceinline__ u16 f2bf(float f) {
  return __builtin_bit_cast(u16, (__bf16)f);
}
static __device__ __forceinline__ u32 pack2(float a, float b) {
  return (u32)f2bf(a) | ((u32)f2bf(b) << 16);
}
static __device__ __forceinline__ bf16x8 ldfrag(const u16* p) {
  return __builtin_bit_cast(bf16x8, *(const u32x4*)p);
}
// async global->LDS, 16B per lane (dst = wave-uniform base + lane*16)
static __device__ __forceinline__ void glds16(const u16* g, u16* l) {
  __builtin_amdgcn_global_load_lds(
      (const __attribute__((address_space(1))) u32*)(const void*)g,
      (__attribute__((address_space(3))) u32*)(void*)l, 16, 0, 0);
}

// Fragment-major layouts, per (b,h) plane of 131072 u16 (2048x64):
//  ksw: (n,d) -> (n>>4)*1024 + (d>>5)*512 + (((d>>3)&3)*16 + (n&15))*8 + (d&7)
//  vsw: (n,d) -> (n>>6)*4096 + (d>>4)*1024 + ((n>>5)&1)*512
//               + (((n>>3)&3)*16 + (d&15))*8 + (n&7)
// One 64-j tile = 4096 u16 contiguous -> LDS image is a straight copy.

// ---------------------------------------------------------------- prep
__global__ void prep_kernel(const float* __restrict__ x,
                            const float* __restrict__ Wq, const float* __restrict__ Wk,
                            const float* __restrict__ Wv, const float* __restrict__ Wo,
                            const float* __restrict__ We1, const float* __restrict__ be1,
                            const float* __restrict__ We2, const float* __restrict__ be2,
                            const float* __restrict__ ebias,
                            u16* __restrict__ xb, u16* __restrict__ wqkv,
                            u16* __restrict__ wob, float* __restrict__ co) {
  const int blk = blockIdx.x, tid = threadIdx.x;
  if (blk < 2048) {
    int i = (blk * 256 + tid) * 4;
    float4 v = *(const float4*)(x + i);
    *(uint2*)(xb + i) = make_uint2(pack2(v.x, v.y), pack2(v.z, v.w));
  } else if (blk < 3072) {
    int i = ((blk - 2048) * 256 + tid) * 4;
    int m = i >> 18;
    int off = i & 262143;
    const float* src = (m == 0) ? Wq : ((m == 1) ? Wk : ((m == 2) ? Wv : Wo));
    u16* dst = (m < 3) ? (wqkv + (size_t)m * 262144) : wob;
    float4 v = *(const float4*)(src + off);
    *(uint2*)(dst + off) = make_uint2(pack2(v.x, v.y), pack2(v.z, v.w));
  } else {
    const int e = tid & 15, h = tid >> 4;
    if (tid < 128) {
      co[49 + e * 8 + h] = 0.0f;
      if (h == 0) { co[17 + e] = 0.0f; co[33 + e] = 0.0f; }
    }
    __syncthreads();
    if (tid < 128) {
      float w1 = We1[e], b1 = be1[e], w2 = We2[h * 16 + e];
      float u0 = b1, u1 = w1 + b1;
      bool on  = (u0 >= 0.0f) && (u1 >= 0.0f);
      bool off = (u0 <= 0.0f) && (u1 <= 0.0f);
      bool crossing = (!on) && (!off);
      float ca = on ? (w2 * b1) : (crossing ? 0.5f * w2 * b1 : 0.0f);
      float cb = on ? (w2 * w1) : (crossing ? 0.5f * w2 * w1 : 0.0f);
      #pragma unroll
      for (int d = 1; d < 16; d <<= 1) { ca += __shfl_xor(ca, d); cb += __shfl_xor(cb, d); }
      if (e == 0) { co[h] = (be2[h] + ca) * L2E; co[8 + h] = (ebias[h] + cb) * L2E; }
      unsigned long long msk = __ballot(crossing);
      int midx = __popcll(msk & 0xFFFFull & ((1ull << e) - 1ull));
      int mcnt = __popcll(msk & 0xFFFFull);
      if (crossing) {
        co[49 + midx * 8 + h] = 0.5f * w2 * L2E;
        if (h == 0) { co[17 + midx] = w1; co[33 + midx] = b1; }
      }
      if (tid == 0) ((int*)co)[16] = mcnt;
    }
  }
}

// ---------------------------------------------------------------- k1: QKV GEMM 64x128
#define LDA 40
__global__ __launch_bounds__(256) void gemm_qkv_kernel(
    const u16* __restrict__ A, const u16* __restrict__ Bm,
    const float* __restrict__ bq, const float* __restrict__ bk, const float* __restrict__ bv,
    u16* __restrict__ qh, u16* __restrict__ ksw, u16* __restrict__ vsw)
{
  __shared__ u16 sm[64 * LDA + 128 * LDA];   // As | Bs, reused by epilogue
  u16* As = sm;
  u16* Bs = sm + 64 * LDA;
  const int tid = threadIdx.x;
  const int lane = tid & 63, w = tid >> 6;
  const int q = lane >> 4, l15 = lane & 15;
  const int m0 = blockIdx.y * 64;
  const int n0 = blockIdx.x * 128;

  f32x4 acc[4][2];
  f32x4 zero = {0.f, 0.f, 0.f, 0.f};
  #pragma unroll
  for (int i = 0; i < 4; i++) { acc[i][0] = zero; acc[i][1] = zero; }

  const bool isA = tid < 128;
  const int arow_ = tid >> 1, ahalf = tid & 1;
  const int brow = tid - 128;
  const u16* ga = A  + (size_t)(m0 + arow_) * EMB + ahalf * 16;
  const u16* gb = Bm + (size_t)(n0 + brow) * EMB;
  u16* la = &As[arow_ * LDA + ahalf * 16];
  u16* lb = &Bs[brow * LDA];

  u32x4 p0, p1, p2, p3;
  if (isA) {
    p0 = *(const u32x4*)(ga); p1 = *(const u32x4*)(ga + 8); ga += 32;
  } else {
    p0 = *(const u32x4*)(gb);      p1 = *(const u32x4*)(gb + 8);
    p2 = *(const u32x4*)(gb + 16); p3 = *(const u32x4*)(gb + 24); gb += 32;
  }

  for (int k0 = 0; k0 < EMB; k0 += 32) {
    __syncthreads();
    if (isA) { *(u32x4*)(la) = p0; *(u32x4*)(la + 8) = p1; }
    else {
      *(u32x4*)(lb)      = p0; *(u32x4*)(lb + 8)  = p1;
      *(u32x4*)(lb + 16) = p2; *(u32x4*)(lb + 24) = p3;
    }
    __syncthreads();
    if (k0 + 32 < EMB) {
      if (isA) { p0 = *(const u32x4*)(ga); p1 = *(const u32x4*)(ga + 8); ga += 32; }
      else {
        p0 = *(const u32x4*)(gb);      p1 = *(const u32x4*)(gb + 8);
        p2 = *(const u32x4*)(gb + 16); p3 = *(const u32x4*)(gb + 24); gb += 32;
      }
    }
    bf16x8 af[4], bfr[2];
    #pragma unroll
    for (int mi = 0; mi < 4; mi++)
      af[mi] = ldfrag(&As[(mi*16 + l15) * LDA + q*8]);
    #pragma unroll
    for (int ni = 0; ni < 2; ni++)
      bfr[ni] = ldfrag(&Bs[(w*32 + ni*16 + l15) * LDA + q*8]);
    #pragma unroll
    for (int mi = 0; mi < 4; mi++)
      #pragma unroll
      for (int ni = 0; ni < 2; ni++)
        acc[mi][ni] = MFMA16(af[mi], bfr[ni], acc[mi][ni]);
  }

  // -------- epilogue: LDS-staged, per-head coalesced stores --------
  const int mat = n0 >> 9;                // 0:Q 1:K 2:V
  const float* bias = (mat == 0) ? bq : ((mat == 1) ? bk : bv);
  const float mul = (mat == 0) ? 0.125f * L2E : 1.0f;
  const int b_ = m0 >> 11;
  const int nbase = m0 & 2047;

  #pragma unroll
  for (int p = 0; p < 2; p++) {           // one head per pass
    __syncthreads();
    if ((w >> 1) == p) {
      #pragma unroll
      for (int ni = 0; ni < 2; ni++) {
        const int dd = (w & 1) * 32 + ni * 16 + l15;
        const float bsv = bias[(n0 & 511) + (w * 32 + ni * 16 + l15)];
        #pragma unroll
        for (int mi = 0; mi < 4; mi++) {
          #pragma unroll
          for (int r = 0; r < 4; r++) {
            const int nr = mi * 16 + q * 4 + r;        // n rel. to nbase
            const float val = (acc[mi][ni][r] + bsv) * mul;
            int idx;
            if (mat == 0)      idx = nr * 64 + dd;
            else if (mat == 1) idx = (nr >> 4) * 1024 + ((dd >> 5) << 9)
                                   + ((((dd >> 3) & 3) * 16 + (nr & 15)) << 3) + (dd & 7);
            else               idx = ((dd >> 4) << 10) + (((nr >> 5) & 1) << 9)
                                   + ((((nr >> 3) & 3) * 16 + (dd & 15)) << 3) + (nr & 7);
            sm[idx] = f2bf(val);
          }
        }
      }
    }
    __syncthreads();
    const int hh = ((n0 & 511) >> 6) + p;
    u16* gdst;
    if (mat == 0)      gdst = qh  + ((size_t)(b_ * NH + hh) * SEQ + nbase) * HD;
    else if (mat == 1) gdst = ksw + (size_t)(b_ * NH + hh) * 131072 + (nbase >> 4) * 1024;
    else               gdst = vsw + (size_t)(b_ * NH + hh) * 131072 + (nbase >> 6) * 4096;
    *(u32x4*)(gdst + tid * 16)     = *(const u32x4*)(sm + tid * 16);
    *(u32x4*)(gdst + tid * 16 + 8) = *(const u32x4*)(sm + tid * 16 + 8);
  }
}

// ---------------------------------------------------------------- k3: out GEMM 64x64
__global__ __launch_bounds__(256) void gemm_out_kernel(
    const u16* __restrict__ A, const u16* __restrict__ Bm,
    const float* __restrict__ bo, float* __restrict__ out)
{
  __shared__ u16 As[64 * LDA];
  __shared__ u16 Bs[64 * LDA];
  const int tid = threadIdx.x;
  const int lane = tid & 63, w = tid >> 6;
  const int q = lane >> 4, l15 = lane & 15;
  const int m0 = blockIdx.y * 64;
  const int n0 = blockIdx.x * 64;

  f32x4 acc[4];
  f32x4 zero = {0.f, 0.f, 0.f, 0.f};
  #pragma unroll
  for (int i = 0; i < 4; i++) acc[i] = zero;

  const bool isA = tid < 128;
  const int row = isA ? (tid >> 1) : ((tid - 128) >> 1);
  const int half = tid & 1;
  const u16* g = (isA ? A + (size_t)(m0 + row) * EMB : Bm + (size_t)(n0 + row) * EMB)
               + half * 16;
  u16* l = (isA ? &As[row * LDA] : &Bs[row * LDA]) + half * 16;

  u32x4 p0 = *(const u32x4*)(g);
  u32x4 p1 = *(const u32x4*)(g + 8);
  g += 32;

  for (int k0 = 0; k0 < EMB; k0 += 32) {
    __syncthreads();
    *(u32x4*)(l) = p0; *(u32x4*)(l + 8) = p1;
    __syncthreads();
    if (k0 + 32 < EMB) {
      p0 = *(const u32x4*)(g); p1 = *(const u32x4*)(g + 8); g += 32;
    }
    bf16x8 af[4], bfr;
    #pragma unroll
    for (int mi = 0; mi < 4; mi++)
      af[mi] = ldfrag(&As[(mi*16 + l15) * LDA + q*8]);
    bfr = ldfrag(&Bs[(w*16 + l15) * LDA + q*8]);
    #pragma unroll
    for (int mi = 0; mi < 4; mi++)
      acc[mi] = MFMA16(af[mi], bfr, acc[mi]);
  }

  int col = n0 + w*16 + l15;
  float bsv = bo[col];
  #pragma unroll
  for (int mi = 0; mi < 4; mi++) {
    int rowb = m0 + mi*16 + q*4;
    #pragma unroll
    for (int r = 0; r < 4; r++)
      out[(size_t)(rowb + r) * EMB + col] = acc[mi][r] + bsv;
  }
}

// ---------------------------------------------------------------- k2: flash (glds dbuf)
// 256 thr = 4 waves. Wave w: i-rows i0+w*16, full j (32 iters of 64 j).
// K/V tiles staged once per block (glds, double-buffered). Frags via ds_read_b128.
template<int MT>
struct FlashCtx {
  const u16 *kgp, *vgp;        // (b,h) plane base, u16
  const float* arow;           // adjacency row base for this wave
  bf16x8 qf0, qf1;
  float Ah, Bh;
  float ctr[MT], dtr[MT], wtr[MT];
  int lane, w, q, l15;
};

template<int MT>
static __device__ __forceinline__ void flash_stage(const FlashCtx<MT>& c,
                                                   u16* Kb, u16* Vb, int it) {
  // wave w copies bytes [w*2048, w*2048+2048) of the 8KB tile, 2 glds each
  const int o = c.w * 1024 + c.lane * 8;   // u16 units
  const u16* kg = c.kgp + it * 4096;
  const u16* vg = c.vgp + it * 4096;
  glds16(kg + o,       Kb + o);
  glds16(kg + o + 512, Kb + o + 512);
  glds16(vg + o,       Vb + o);
  glds16(vg + o + 512, Vb + o + 512);
}

template<int MT>
static __device__ __forceinline__ void flash_iter(
    const FlashCtx<MT>& c, int it, u16* Kb, u16* Vb, u16* nKb, u16* nVb,
    u16* psw, float4* avc, float4* avn, f32x4* O, float& lsum)
{
  __syncthreads();                       // gates buf(it); drains glds(it) issued last iter
  if (it + 1 < 32) flash_stage(c, nKb, nVb, it + 1);
  const int nx = (it + 1 < 32) ? it + 1 : 31;
  #pragma unroll
  for (int jt = 0; jt < 4; jt++)
    avn[jt] = *(const float4*)(c.arow + nx * 64 + jt * 16);
  __builtin_amdgcn_sched_barrier(0);     // keep prefetch above compute

  f32x4 zero = {0.f, 0.f, 0.f, 0.f};
  const int lo = c.lane * 8;

  // S^T = MFMA(kf, qf)
  f32x4 S[4];
  #pragma unroll
  for (int jt = 0; jt < 4; jt++) {
    bf16x8 kf0 = ldfrag(Kb + jt * 1024 + lo);
    bf16x8 kf1 = ldfrag(Kb + jt * 1024 + 512 + lo);
    f32x4 s = MFMA16(kf0, c.qf0, zero);
    S[jt] = MFMA16(kf1, c.qf1, s);
  }

  // halves: edge+exp+P-write for 2 jt, then P-read + 4 PV MFMAs
  #pragma unroll
  for (int half = 0; half < 2; half++) {
    #pragma unroll
    for (int jj = 0; jj < 2; jj++) {
      const int jt = half * 2 + jj;
      float p[4];
      #pragma unroll
      for (int r = 0; r < 4; r++) {
        float a = ((const float*)&avc[jt])[r];
        float e = fmaf(a, c.Bh, c.Ah);
        #pragma unroll
        for (int t = 0; t < MT; t++)
          e = fmaf(fabsf(fmaf(a, c.ctr[t], c.dtr[t])), c.wtr[t], e);
        p[r] = __builtin_amdgcn_exp2f(S[jt][r] + e);
        lsum += p[r];
      }
      *(uint2*)(psw + c.l15 * 72 + jt * 16 + c.q * 4) =
          make_uint2(pack2(p[0], p[1]), pack2(p[2], p[3]));
    }
    bf16x8 pf = ldfrag(psw + c.l15 * 72 + half * 32 + c.q * 8);
    #pragma unroll
    for (int dt = 0; dt < 4; dt++) {
      bf16x8 vf = ldfrag(Vb + dt * 1024 + half * 512 + lo);
      O[dt] = MFMA16(vf, pf, O[dt]);
    }
  }
}

template<int MT>
__device__ __forceinline__ void flash_body(
    u16* Kb0, u16* Kb1, u16* Vb0, u16* Vb1, u16* Pb,
    const u16* __restrict__ qh, const u16* __restrict__ ksw, const u16* __restrict__ vsw,
    const float* __restrict__ adj, const float* __restrict__ coeff, u16* __restrict__ om)
{
  const int tid = threadIdx.x, lane = tid & 63, w = tid >> 6;
  const int q = lane >> 4, l15 = lane & 15;
  const int i0 = blockIdx.x * 64;
  const int h = blockIdx.y, b = blockIdx.z;
  const int bh = b * NH + h;
  const int iw = i0 + w * 16;

  FlashCtx<MT> c;
  c.lane = lane; c.w = w; c.q = q; c.l15 = l15;
  c.Ah = coeff[h]; c.Bh = coeff[8 + h];
  #pragma unroll
  for (int t = 0; t < MT; t++) {
    c.ctr[t] = coeff[17 + t];
    c.dtr[t] = coeff[33 + t];
    c.wtr[t] = coeff[49 + t * 8 + h];
  }
  const u16* qrow = qh + ((size_t)bh * SEQ + iw + l15) * HD;
  c.qf0 = ldfrag(qrow + q * 8);
  c.qf1 = ldfrag(qrow + 32 + q * 8);
  c.kgp = ksw + (size_t)bh * 131072;
  c.vgp = vsw + (size_t)bh * 131072;
  c.arow = adj + ((size_t)b * SEQ + iw + l15) * SEQ + q * 4;

  f32x4 O[4];
  f32x4 zero = {0.f, 0.f, 0.f, 0.f};
  #pragma unroll
  for (int dt = 0; dt < 4; dt++) O[dt] = zero;
  float lsum = 0.0f;

  u16* psw = Pb + w * 1152;   // 16*72 per wave

  // prologue: stage tile 0 + adjacency 0
  flash_stage(c, Kb0, Vb0, 0);
  float4 avA[4], avB[4];
  #pragma unroll
  for (int jt = 0; jt < 4; jt++)
    avA[jt] = *(const float4*)(c.arow + jt * 16);

  #pragma unroll 1
  for (int it2 = 0; it2 < 32; it2 += 2) {
    flash_iter(c, it2,     Kb0, Vb0, Kb1, Vb1, psw, avA, avB, O, lsum);
    flash_iter(c, it2 + 1, Kb1, Vb1, Kb0, Vb0, psw, avB, avA, O, lsum);
  }

  // full row-sum for i=l15 (reduce across the 4 quads)
  lsum += __shfl_xor(lsum, 16);
  lsum += __shfl_xor(lsum, 32);
  float rl = 1.0f / lsum;

  u16* orow = om + ((size_t)b * SEQ + iw + l15) * EMB + h * HD + q * 4;
  #pragma unroll
  for (int dt = 0; dt < 4; dt++) {
    float v0 = O[dt][0] * rl, v1 = O[dt][1] * rl;
    float v2 = O[dt][2] * rl, v3 = O[dt][3] * rl;
    *(uint2*)(orow + dt * 16) = make_uint2(pack2(v0, v1), pack2(v2, v3));
  }
}

__global__ __launch_bounds__(256, 3) void flash_kernel(
    const u16* __restrict__ qh, const u16* __restrict__ ksw, const u16* __restrict__ vsw,
    const float* __restrict__ adj, const float* __restrict__ coeff, u16* __restrict__ om)
{
  __shared__ __align__(16) u16 Kb[2][4096];   // 16 KB
  __shared__ __align__(16) u16 Vb[2][4096];   // 16 KB
  __shared__ __align__(16) u16 Pb[4608];      //  9 KB
  const int mt = ((const int*)coeff)[16];
  if (mt <= 4)
    flash_body<4>(Kb[0], Kb[1], Vb[0], Vb[1], Pb, qh, ksw, vsw, adj, coeff, om);
  else if (mt <= 8)
    flash_body<8>(Kb[0], Kb[1], Vb[0], Vb[1], Pb, qh, ksw, vsw, adj, coeff, om);
  else
    flash_body<16>(Kb[0], Kb[1], Vb[0], Vb[1], Pb, qh, ksw, vsw, adj, coeff, om);
}

// ---------------------------------------------------------------- launch
extern "C" void kernel_launch(void* const* d_in, const int* in_sizes, int n_in,
                              void* d_out, int out_size, void* d_ws, size_t ws_size,
                              hipStream_t stream) {
  const float* x     = (const float*)d_in[0];
  const float* adj   = (const float*)d_in[1];
  const float* Wq    = (const float*)d_in[2];
  const float* bq    = (const float*)d_in[3];
  const float* Wk    = (const float*)d_in[4];
  const float* bk    = (const float*)d_in[5];
  const float* Wv    = (const float*)d_in[6];
  const float* bv    = (const float*)d_in[7];
  const float* Wo    = (const float*)d_in[8];
  const float* bo    = (const float*)d_in[9];
  const float* We1   = (const float*)d_in[10];
  const float* be1   = (const float*)d_in[11];
  const float* We2   = (const float*)d_in[12];
  const float* be2   = (const float*)d_in[13];
  const float* ebias = (const float*)d_in[14];
  float* out = (float*)d_out;

  char* ws = (char*)d_ws;
  u16*   xb   = (u16*)(ws + 0);          //  4 MB  x bf16
  u16*   wqkv = (u16*)(ws + 4194304);    //  1.5MB Wq|Wk|Wv bf16
  u16*   wob  = (u16*)(ws + 5767168);    //  0.5MB Wo bf16
  u16*   qh   = (u16*)(ws + 6291456);    //  4 MB  (B,H,N,64) row-major
  u16*   ksw  = (u16*)(ws + 10485760);   //  4 MB  fragment-major K
  u16*   vsw  = (u16*)(ws + 14680064);   //  4 MB  fragment-major V
  u16*   om   = (u16*)(ws + 18874368);   //  4 MB  (B,N,512) bf16
  float* co   = (float*)(ws + 23068672); //  1 KB  edge coefficients
  if (ws_size < 23069696) return;

  prep_kernel<<<3073, 256, 0, stream>>>(x, Wq, Wk, Wv, Wo, We1, be1, We2, be2, ebias,
                                        xb, wqkv, wob, co);
  gemm_qkv_kernel<<<dim3(12, 64), 256, 0, stream>>>(xb, wqkv, bq, bk, bv, qh, ksw, vsw);
  flash_kernel<<<dim3(32, NH, NB), 256, 0, stream>>>(qh, ksw, vsw, adj, co, om);
  gemm_out_kernel<<<dim3(8, 64), 256, 0, stream>>>(om, wob, bo, out);
}